// Round 2
// baseline (35099.985 us; speedup 1.0000x reference)
//
#include <hip/hip_runtime.h>
#include <hip/hip_bf16.h>

typedef __bf16 bf16;
typedef __bf16 bf16x8 __attribute__((ext_vector_type(8)));
typedef __bf16 bf16x4 __attribute__((ext_vector_type(4)));
typedef float f32x4 __attribute__((ext_vector_type(4)));

#define WI_SLAB (16384UL*512UL)
#define WP_SLAB (512UL*4096UL)
#define XP_SLAB (128UL*16UL*16384UL)

// ws byte-offset plan
#define OFF_WI 0UL                       // Wi bf16: 67108864
#define OFF_WS 67108864UL                // Ws bf16: 67108864
#define OFF_WP 134217728UL               // Wp bf16: 16777216
#define OFF_A0 150994944UL               // 2097152
#define OFF_A1F 153092096UL
#define OFF_A1B 155189248UL
#define OFF_XP 157286400UL               // 134217728
#define OFF_H  291504128UL               // hfin: 2*16*512*2 = 32768
#define OFF_BAR 291536896UL              // barrier words (reuses old cell region)
#define OFF_AB 292061184UL               // abuf: 2*16*4096*2 = 262144

__device__ __forceinline__ float sigm_(float x){ return 1.f/(1.f + __expf(-x)); }
__device__ __forceinline__ float tanh_(float x){ return 1.f - 2.f/(__expf(2.f*x) + 1.f); }

// ---------- generic f32 -> bf16 cast ----------
__global__ __launch_bounds__(256) void k_cast(const float* __restrict__ src,
                                              bf16* __restrict__ dst, int n4){
  int i = blockIdx.x*blockDim.x + threadIdx.x;
  int stride = gridDim.x*blockDim.x;
  const float4* s4 = (const float4*)src;
  bf16x4* d4 = (bf16x4*)dst;
  for (; i < n4; i += stride){
    float4 v = s4[i];
    bf16x4 o = {(bf16)v.x, (bf16)v.y, (bf16)v.z, (bf16)v.w};
    d4[i] = o;
  }
}

// ---------- x (B,T,512) f32 -> A0 (t,b,512) bf16 ----------
__global__ __launch_bounds__(256) void k_castx(const float* __restrict__ x,
                                               bf16* __restrict__ dst){
  int g = blockIdx.x*256 + threadIdx.x;
  int d = (g & 127) * 4;
  int r = g >> 7;
  int b = r >> 7, t = r & 127;
  float4 v = ((const float4*)x)[g];
  bf16x4 o = {(bf16)v.x, (bf16)v.y, (bf16)v.z, (bf16)v.w};
  *(bf16x4*)(dst + (size_t)(t*16 + b)*512 + d) = o;
}

// ---------- layer-0 output (B,T,1024) f32 -> A1f/A1b (t,b,512) bf16 ----------
__global__ __launch_bounds__(256) void k_castout(const float* __restrict__ out0,
                                                 bf16* __restrict__ a1f,
                                                 bf16* __restrict__ a1b){
  int g = blockIdx.x*256 + threadIdx.x;
  int hh = (g & 255) * 4;
  int r = g >> 8;
  int b = r >> 7, t = r & 127;
  float4 v = ((const float4*)out0)[g];
  bf16x4 o = {(bf16)v.x, (bf16)v.y, (bf16)v.z, (bf16)v.w};
  if (hh < 512) *(bf16x4*)(a1f + (size_t)(t*16 + b)*512 + hh) = o;
  else          *(bf16x4*)(a1b + (size_t)(t*16 + b)*512 + hh - 512) = o;
}

// ---------- input GEMM: Xp[m][n] = sum_k A[m][k]*W[n][k] + bias[n] ----------
__global__ __launch_bounds__(256) void k_gemm_in(const bf16* __restrict__ A,
                                                 const bf16* __restrict__ W,
                                                 const float* __restrict__ bias,
                                                 bf16* __restrict__ Xp){
  int lane = threadIdx.x & 63, w = threadIdx.x >> 6;
  int n0 = blockIdx.x*256 + w*64;
  int m0 = blockIdx.y*64;
  int lm = lane & 15, lq = lane >> 4;
  f32x4 acc[4][4] = {};
  for (int kk = 0; kk < 512; kk += 32){
    int kc = kk + lq*8;
    bf16x8 af[4];
#pragma unroll
    for (int mt = 0; mt < 4; mt++)
      af[mt] = *(const bf16x8*)(A + (size_t)(m0 + mt*16 + lm)*512 + kc);
#pragma unroll
    for (int nt = 0; nt < 4; nt++){
      bf16x8 bfr = *(const bf16x8*)(W + (size_t)(n0 + nt*16 + lm)*512 + kc);
#pragma unroll
      for (int mt = 0; mt < 4; mt++)
        acc[mt][nt] = __builtin_amdgcn_mfma_f32_16x16x32_bf16(af[mt], bfr, acc[mt][nt], 0, 0, 0);
    }
  }
#pragma unroll
  for (int mt = 0; mt < 4; mt++)
#pragma unroll
    for (int nt = 0; nt < 4; nt++)
#pragma unroll
      for (int r = 0; r < 4; r++){
        int row = m0 + mt*16 + lq*4 + r;
        int col = n0 + nt*16 + lm;
        Xp[(size_t)row*16384 + col] = (bf16)(acc[mt][nt][r] + bias[col]);
      }
}

// ---------- device-scope grid barrier (all 256 wgs resident) ----------
__device__ __forceinline__ void gbar(int* cnt, int* gen){
  __threadfence();
  __syncthreads();
  if (threadIdx.x == 0){
    int g = __hip_atomic_load(gen, __ATOMIC_RELAXED, __HIP_MEMORY_SCOPE_AGENT);
    int a = __hip_atomic_fetch_add(cnt, 1, __ATOMIC_ACQ_REL, __HIP_MEMORY_SCOPE_AGENT);
    if (a == 255){
      __hip_atomic_store(cnt, 0, __ATOMIC_RELAXED, __HIP_MEMORY_SCOPE_AGENT);
      __hip_atomic_fetch_add(gen, 1, __ATOMIC_RELEASE, __HIP_MEMORY_SCOPE_AGENT);
    } else {
      while (__hip_atomic_load(gen, __ATOMIC_ACQUIRE, __HIP_MEMORY_SCOPE_AGENT) == g)
        __builtin_amdgcn_s_sleep(1);
    }
  }
  __syncthreads();
  __threadfence();
}

// ---------- persistent recurrence kernel (one layer, both dirs) ----------
// grid: 256 wgs x 256 thr, 1 wg/CU. wg -> dir = wg>>7, sub = wg&127.
// All wgs: gates for columns [sub*32, sub*32+32), Ws slice (128KB) in LDS.
// wgs with sub<32 additionally: projection h-tile sub*16..+16, Wp in VGPRs.
__global__ __launch_bounds__(256, 1) void k_persist(
    const bf16* __restrict__ Wsl, const bf16* __restrict__ Wpl,
    const bf16* __restrict__ Xp, bf16* __restrict__ abuf,
    bf16* __restrict__ hfin, const int* __restrict__ len,
    float* __restrict__ out, int* __restrict__ bar, int l)
{
  extern __shared__ char smem[];
  bf16* ws_lds  = (bf16*)smem;                     // 128 rows x 520 = 133120 B
  bf16* h_lds   = (bf16*)(smem + 133120);          // 16 x 520 = 16640 B
  float* pre_lds = (float*)(smem + 149760);        // [4g][32c][20b] f32 = 10240 B
  float* red_lds = pre_lds;                        // proj reduction reuse [4w][16h][20b]

  const int tid = threadIdx.x;
  const int lane = tid & 63, w = tid >> 6;
  const int lm = lane & 15, lq = lane >> 4;
  const int wg = blockIdx.x;
  const int dir = wg >> 7;
  const int sub = wg & 127;
  const int c0g = sub * 32;

  const bf16* Wsd = Wsl + (size_t)dir * WI_SLAB;
  const bf16* Wpd = Wpl + (size_t)dir * WP_SLAB;
  const bf16* Xpd = Xp + (size_t)dir * XP_SLAB;
  const bf16* ad  = abuf + (size_t)dir * 16 * 4096;

  int* cnt = bar; int* gen = bar + 16;

  // ---- Ws slice -> LDS (once per layer) ----
  {
    int rr = tid >> 1, half = tid & 1;
    int g = rr >> 5, c = rr & 31;
    const bf16* src = Wsd + ((size_t)(g*4096 + c0g + c))*512 + half*256;
    bf16* dst = ws_lds + rr*520 + half*256;
#pragma unroll
    for (int i = 0; i < 32; i++)
      ((bf16x8*)dst)[i] = ((const bf16x8*)src)[i];
  }
  // ---- zero h_lds ----
  for (int i = tid; i < 4160; i += 256) ((unsigned int*)h_lds)[i] = 0u;

  // ---- proj weights -> VGPRs (sub<32): wave w owns K-slice [w*1024, +1024) ----
  bf16x8 wp[32];
  const int h0 = (sub & 31) * 16;
  if (sub < 32){
    const bf16* wrow = Wpd + (size_t)(h0 + lm)*4096 + w*1024 + lq*8;
#pragma unroll
    for (int i = 0; i < 32; i++)
      wp[i] = *(const bf16x8*)(wrow + i*32);
  }

  float cs0 = 0.f, cs1 = 0.f;                 // cell state, thread-owned
  const int bb = tid >> 4;                    // cell-update batch row
  const int cc = tid & 15;                    // cell-update col (and +16)
  const int Lb = len[bb];
  const int Lpb = len[tid & 15];              // proj finalize batch row
  __syncthreads();

  for (int s = 0; s < 128; s++){
    // ---- stage h(s) into LDS ----
    if (s > 0){
      const bf16* src = hfin + (size_t)(dir*16 + bb)*512 + cc*32;
      bf16* dst = h_lds + bb*520 + cc*32;
      *(bf16x8*)(dst)      = *(const bf16x8*)(src);
      *(bf16x8*)(dst + 8)  = *(const bf16x8*)(src + 8);
      *(bf16x8*)(dst + 16) = *(const bf16x8*)(src + 16);
      *(bf16x8*)(dst + 24) = *(const bf16x8*)(src + 24);
      __syncthreads();
    }
    // ---- gates MFMA: wave w = gate w, 2 col-tiles ----
    f32x4 acc0 = {}, acc1 = {};
#pragma unroll
    for (int kk = 0; kk < 16; kk++){
      int kc = kk*32 + lq*8;
      bf16x8 af = *(const bf16x8*)(h_lds + lm*520 + kc);
      bf16x8 b0 = *(const bf16x8*)(ws_lds + (w*32 + lm)*520 + kc);
      bf16x8 b1 = *(const bf16x8*)(ws_lds + (w*32 + 16 + lm)*520 + kc);
      acc0 = __builtin_amdgcn_mfma_f32_16x16x32_bf16(af, b0, acc0, 0, 0, 0);
      acc1 = __builtin_amdgcn_mfma_f32_16x16x32_bf16(af, b1, acc1, 0, 0, 0);
    }
    *(f32x4*)(pre_lds + w*640 + lm*20 + lq*4)        = acc0;
    *(f32x4*)(pre_lds + w*640 + (16 + lm)*20 + lq*4) = acc1;
    __syncthreads();
    // ---- cell update ----
    {
      bool valid = s < Lb;
      int u = dir ? (Lb - 1 - s) : s;
      u = u < 0 ? 0 : u;
      const bf16* xrow = Xpd + (size_t)(u*16 + bb)*16384 + c0g;
      {
        float p0 = pre_lds[0*640 + cc*20 + bb] + (float)xrow[0*4096 + cc];
        float p1 = pre_lds[1*640 + cc*20 + bb] + (float)xrow[1*4096 + cc];
        float p2 = pre_lds[2*640 + cc*20 + bb] + (float)xrow[2*4096 + cc];
        float p3 = pre_lds[3*640 + cc*20 + bb] + (float)xrow[3*4096 + cc];
        float cn = fminf(fmaxf(sigm_(p0)*tanh_(p2) + sigm_(p1)*cs0, -3.f), 3.f);
        if (valid) cs0 = cn;
        abuf[(size_t)(dir*16 + bb)*4096 + c0g + cc] = (bf16)(sigm_(p3) * tanh_(cn));
      }
      {
        int c2 = cc + 16;
        float p0 = pre_lds[0*640 + c2*20 + bb] + (float)xrow[0*4096 + c2];
        float p1 = pre_lds[1*640 + c2*20 + bb] + (float)xrow[1*4096 + c2];
        float p2 = pre_lds[2*640 + c2*20 + bb] + (float)xrow[2*4096 + c2];
        float p3 = pre_lds[3*640 + c2*20 + bb] + (float)xrow[3*4096 + c2];
        float cn = fminf(fmaxf(sigm_(p0)*tanh_(p2) + sigm_(p1)*cs1, -3.f), 3.f);
        if (valid) cs1 = cn;
        abuf[(size_t)(dir*16 + bb)*4096 + c0g + c2] = (bf16)(sigm_(p3) * tanh_(cn));
      }
    }
    gbar(cnt, gen);            // a visible to all
    // ---- projection (sub<32): full K=4096, wave-split 1024 ----
    if (sub < 32){
      f32x4 pacc = {};
#pragma unroll
      for (int kk = 0; kk < 32; kk++){
        bf16x8 af = *(const bf16x8*)(ad + (size_t)lm*4096 + w*1024 + kk*32 + lq*8);
        pacc = __builtin_amdgcn_mfma_f32_16x16x32_bf16(af, wp[kk], pacc, 0, 0, 0);
      }
      *(f32x4*)(red_lds + w*320 + lm*20 + lq*4) = pacc;
      __syncthreads();
      {
        int hh = tid >> 4, b = tid & 15;
        float hn_raw = red_lds[0*320 + hh*20 + b] + red_lds[1*320 + hh*20 + b]
                     + red_lds[2*320 + hh*20 + b] + red_lds[3*320 + hh*20 + b];
        bool valid = s < Lpb;
        int idx = (dir*16 + b)*512 + h0 + hh;
        float hold = (float)hfin[idx];
        float hn = valid ? fminf(fmaxf(hn_raw, -3.f), 3.f) : hold;
        hfin[idx] = (bf16)hn;
        if (valid){
          int u = dir ? (Lpb - 1 - s) : s;
          size_t o = ((size_t)(l*16 + b)*128 + u)*1024 + (size_t)dir*512 + h0 + hh;
          float val = hn;
          if (l) val += out[((size_t)b*128 + u)*1024 + (size_t)dir*512 + h0 + hh];
          out[o] = val;
        }
      }
    }
    gbar(cnt, gen);            // h visible to all
  }
}

extern "C" void kernel_launch(void* const* d_in, const int* in_sizes, int n_in,
                              void* d_out, int out_size, void* d_ws, size_t ws_size,
                              hipStream_t stream) {
  const float* x   = (const float*)d_in[0];
  const int*   sl  = (const int*)d_in[1];
  const float* Wi  = (const float*)d_in[2];
  const float* Ws  = (const float*)d_in[3];
  const float* bia = (const float*)d_in[4];
  const float* Wp  = (const float*)d_in[5];
  float* out = (float*)d_out;
  char* ws = (char*)d_ws;

  bf16* WiB = (bf16*)(ws + OFF_WI);
  bf16* WsB = (bf16*)(ws + OFF_WS);
  bf16* WpB = (bf16*)(ws + OFF_WP);
  bf16* A0  = (bf16*)(ws + OFF_A0);
  bf16* A1F = (bf16*)(ws + OFF_A1F);
  bf16* A1B = (bf16*)(ws + OFF_A1B);
  bf16* XpB = (bf16*)(ws + OFF_XP);
  bf16* hfin = (bf16*)(ws + OFF_H);
  bf16* abuf = (bf16*)(ws + OFF_AB);
  int* bar = (int*)(ws + OFF_BAR);

  hipFuncSetAttribute((const void*)k_persist,
                      hipFuncAttributeMaxDynamicSharedMemorySize, 160000);

  // weight casts
  k_cast<<<2048, 256, 0, stream>>>(Wi, WiB, 8388608);
  k_cast<<<2048, 256, 0, stream>>>(Ws, WsB, 8388608);
  k_cast<<<2048, 256, 0, stream>>>(Wp, WpB, 2097152);

  hipMemsetAsync(d_out, 0, (size_t)out_size*4, stream);
  hipMemsetAsync(bar, 0, 128, stream);

  // ----- layer 0 -----
  k_castx<<<1024, 256, 0, stream>>>(x, A0);
  k_gemm_in<<<dim3(64,32), 256, 0, stream>>>(A0, WiB,           bia,          XpB);
  k_gemm_in<<<dim3(64,32), 256, 0, stream>>>(A0, WiB + WI_SLAB, bia + 16384,  XpB + XP_SLAB);
  k_persist<<<256, 256, 160000, stream>>>(WsB, WpB, XpB, abuf, hfin, sl, out, bar, 0);

  // ----- layer 1 -----
  k_castout<<<2048, 256, 0, stream>>>(out, A1F, A1B);
  k_gemm_in<<<dim3(64,32), 256, 0, stream>>>(A1F, WiB + 2*WI_SLAB, bia + 2*16384, XpB);
  k_gemm_in<<<dim3(64,32), 256, 0, stream>>>(A1B, WiB + 3*WI_SLAB, bia + 3*16384, XpB + XP_SLAB);
  k_persist<<<256, 256, 160000, stream>>>(WsB + 2*WI_SLAB, WpB + 2*WP_SLAB, XpB,
                                          abuf, hfin, sl, out, bar, 1);
}

// Round 3
// 9018.044 us; speedup vs baseline: 3.8922x; 3.8922x over previous
//
#include <hip/hip_runtime.h>
#include <hip/hip_bf16.h>

typedef __bf16 bf16;
typedef __bf16 bf16x8 __attribute__((ext_vector_type(8)));
typedef __bf16 bf16x4 __attribute__((ext_vector_type(4)));
typedef float f32x4 __attribute__((ext_vector_type(4)));

#define WI_SLAB (16384UL*512UL)
#define WP_SLAB (512UL*4096UL)
#define XP_SLAB (128UL*16UL*16384UL)

// ws byte-offset plan
#define OFF_WI 0UL                       // Wi bf16: 67108864
#define OFF_WS 67108864UL                // Ws bf16: 67108864
#define OFF_WP 134217728UL               // Wp bf16: 16777216
#define OFF_A0 150994944UL               // 2097152
#define OFF_A1F 153092096UL
#define OFF_A1B 155189248UL
#define OFF_XP 157286400UL               // 134217728
#define OFF_H  291504128UL               // hfin: 2*16*512*2 = 32768
#define OFF_BAR 291536896UL              // flags[256] ints
#define OFF_AB 292061184UL               // abuf: 2*16*4096*2 = 262144

__device__ __forceinline__ float sigm_(float x){ return 1.f/(1.f + __expf(-x)); }
__device__ __forceinline__ float tanh_(float x){ return 1.f - 2.f/(__expf(2.f*x) + 1.f); }

// ---------- generic f32 -> bf16 cast ----------
__global__ __launch_bounds__(256) void k_cast(const float* __restrict__ src,
                                              bf16* __restrict__ dst, int n4){
  int i = blockIdx.x*blockDim.x + threadIdx.x;
  int stride = gridDim.x*blockDim.x;
  const float4* s4 = (const float4*)src;
  bf16x4* d4 = (bf16x4*)dst;
  for (; i < n4; i += stride){
    float4 v = s4[i];
    bf16x4 o = {(bf16)v.x, (bf16)v.y, (bf16)v.z, (bf16)v.w};
    d4[i] = o;
  }
}

// ---------- x (B,T,512) f32 -> A0 (t,b,512) bf16 ----------
__global__ __launch_bounds__(256) void k_castx(const float* __restrict__ x,
                                               bf16* __restrict__ dst){
  int g = blockIdx.x*256 + threadIdx.x;
  int d = (g & 127) * 4;
  int r = g >> 7;
  int b = r >> 7, t = r & 127;
  float4 v = ((const float4*)x)[g];
  bf16x4 o = {(bf16)v.x, (bf16)v.y, (bf16)v.z, (bf16)v.w};
  *(bf16x4*)(dst + (size_t)(t*16 + b)*512 + d) = o;
}

// ---------- layer-0 output (B,T,1024) f32 -> A1f/A1b (t,b,512) bf16 ----------
__global__ __launch_bounds__(256) void k_castout(const float* __restrict__ out0,
                                                 bf16* __restrict__ a1f,
                                                 bf16* __restrict__ a1b){
  int g = blockIdx.x*256 + threadIdx.x;
  int hh = (g & 255) * 4;
  int r = g >> 8;
  int b = r >> 7, t = r & 127;
  float4 v = ((const float4*)out0)[g];
  bf16x4 o = {(bf16)v.x, (bf16)v.y, (bf16)v.z, (bf16)v.w};
  if (hh < 512) *(bf16x4*)(a1f + (size_t)(t*16 + b)*512 + hh) = o;
  else          *(bf16x4*)(a1b + (size_t)(t*16 + b)*512 + hh - 512) = o;
}

// ---------- input GEMM: Xp[m][n] = sum_k A[m][k]*W[n][k] + bias[n] ----------
__global__ __launch_bounds__(256) void k_gemm_in(const bf16* __restrict__ A,
                                                 const bf16* __restrict__ W,
                                                 const float* __restrict__ bias,
                                                 bf16* __restrict__ Xp){
  int lane = threadIdx.x & 63, w = threadIdx.x >> 6;
  int n0 = blockIdx.x*256 + w*64;
  int m0 = blockIdx.y*64;
  int lm = lane & 15, lq = lane >> 4;
  f32x4 acc[4][4] = {};
  for (int kk = 0; kk < 512; kk += 32){
    int kc = kk + lq*8;
    bf16x8 af[4];
#pragma unroll
    for (int mt = 0; mt < 4; mt++)
      af[mt] = *(const bf16x8*)(A + (size_t)(m0 + mt*16 + lm)*512 + kc);
#pragma unroll
    for (int nt = 0; nt < 4; nt++){
      bf16x8 bfr = *(const bf16x8*)(W + (size_t)(n0 + nt*16 + lm)*512 + kc);
#pragma unroll
      for (int mt = 0; mt < 4; mt++)
        acc[mt][nt] = __builtin_amdgcn_mfma_f32_16x16x32_bf16(af[mt], bfr, acc[mt][nt], 0, 0, 0);
    }
  }
#pragma unroll
  for (int mt = 0; mt < 4; mt++)
#pragma unroll
    for (int nt = 0; nt < 4; nt++)
#pragma unroll
      for (int r = 0; r < 4; r++){
        int row = m0 + mt*16 + lq*4 + r;
        int col = n0 + nt*16 + lm;
        Xp[(size_t)row*16384 + col] = (bf16)(acc[mt][nt][r] + bias[col]);
      }
}

// ---------- distributed epoch barrier primitives ----------
// set_flag: one RELEASE store to own word (no RMW, no central line contention).
// poll_flags: one wave polls all 256 flags with RELAXED loads (no buffer_inv
// storm); single acquire fence after success.
__device__ __forceinline__ void set_flag(int* flags, int wg, int ep){
  __syncthreads();   // drains each wave's vmem (compiler emits vmcnt(0) before s_barrier)
  if (threadIdx.x == 0)
    __hip_atomic_store(flags + wg, ep, __ATOMIC_RELEASE, __HIP_MEMORY_SCOPE_AGENT);
}
__device__ __forceinline__ void poll_flags(int* flags, int ep){
  if (threadIdx.x < 64){
    int i0 = threadIdx.x * 4;
    for (;;){
      int f0 = __hip_atomic_load(flags + i0 + 0, __ATOMIC_RELAXED, __HIP_MEMORY_SCOPE_AGENT);
      int f1 = __hip_atomic_load(flags + i0 + 1, __ATOMIC_RELAXED, __HIP_MEMORY_SCOPE_AGENT);
      int f2 = __hip_atomic_load(flags + i0 + 2, __ATOMIC_RELAXED, __HIP_MEMORY_SCOPE_AGENT);
      int f3 = __hip_atomic_load(flags + i0 + 3, __ATOMIC_RELAXED, __HIP_MEMORY_SCOPE_AGENT);
      if (__all((f0 >= ep) && (f1 >= ep) && (f2 >= ep) && (f3 >= ep))) break;
      __builtin_amdgcn_s_sleep(2);
    }
  }
  __syncthreads();
  __builtin_amdgcn_fence(__ATOMIC_ACQUIRE, "agent");
}

// ---------- persistent recurrence kernel (one layer, both dirs) ----------
// grid: 256 wgs x 256 thr, 1 wg/CU. wg -> dir = wg>>7, sub = wg&127.
// All wgs: gates for columns [sub*32, sub*32+32), Ws slice (130KB) in LDS.
// wgs with sub<32 additionally: projection h-tile sub*16..+16, Wp in VGPRs.
// Epochs: step s uses ep1 = l*256+2s+1 (abuf ready), ep2 = ep1+1 (hfin ready).
// Non-proj wgs jump straight to ep2 (monotone flags make >= checks safe).
__global__ __launch_bounds__(256, 1) void k_persist(
    const bf16* __restrict__ Wsl, const bf16* __restrict__ Wpl,
    const bf16* __restrict__ Xp, bf16* __restrict__ abuf,
    bf16* __restrict__ hfin, const int* __restrict__ len,
    float* __restrict__ out, int* __restrict__ flags, int l)
{
  extern __shared__ char smem[];
  bf16* ws_lds  = (bf16*)smem;                     // 128 rows x 520 = 133120 B
  bf16* h_lds   = (bf16*)(smem + 133120);          // 16 x 520 = 16640 B
  float* pre_lds = (float*)(smem + 149760);        // [4g][32c][20b] f32 = 10240 B
  float* red_lds = pre_lds;                        // proj reduction reuse [4w][16h][20b]

  const int tid = threadIdx.x;
  const int lane = tid & 63, w = tid >> 6;
  const int lm = lane & 15, lq = lane >> 4;
  const int wg = blockIdx.x;
  const int dir = wg >> 7;
  const int sub = wg & 127;
  const int c0g = sub * 32;
  const bool isproj = (sub < 32);

  const bf16* Wsd = Wsl + (size_t)dir * WI_SLAB;
  const bf16* Wpd = Wpl + (size_t)dir * WP_SLAB;
  const bf16* Xpd = Xp + (size_t)dir * XP_SLAB;
  const bf16* ad  = abuf + (size_t)dir * 16 * 4096;

  // ---- Ws slice -> LDS (once per layer) ----
  {
    int rr = tid >> 1, half = tid & 1;
    int g = rr >> 5, c = rr & 31;
    const bf16* src = Wsd + ((size_t)(g*4096 + c0g + c))*512 + half*256;
    bf16* dst = ws_lds + rr*520 + half*256;
#pragma unroll
    for (int i = 0; i < 32; i++)
      ((bf16x8*)dst)[i] = ((const bf16x8*)src)[i];
  }
  // ---- zero h_lds ----
  for (int i = tid; i < 4160; i += 256) ((unsigned int*)h_lds)[i] = 0u;

  // ---- proj weights -> VGPRs (sub<32): wave w owns K-slice [w*1024, +1024) ----
  bf16x8 wp[32];
  const int h0 = (sub & 31) * 16;
  if (isproj){
    const bf16* wrow = Wpd + (size_t)(h0 + lm)*4096 + w*1024 + lq*8;
#pragma unroll
    for (int i = 0; i < 32; i++)
      wp[i] = *(const bf16x8*)(wrow + i*32);
  }

  float cs0 = 0.f, cs1 = 0.f;                 // cell state, thread-owned
  const int bb = tid >> 4;                    // cell-update batch row
  const int cc = tid & 15;                    // cell-update col (and +16)
  const int Lb = len[bb];
  const int Lpb = len[tid & 15];              // proj finalize batch row
  __syncthreads();

  for (int s = 0; s < 128; s++){
    const int ep1 = l*256 + s*2 + 1;
    const int ep2 = ep1 + 1;
    // ---- stage h(s) into LDS ----
    if (s > 0){
      const bf16* src = hfin + (size_t)(dir*16 + bb)*512 + cc*32;
      bf16* dst = h_lds + bb*520 + cc*32;
      *(bf16x8*)(dst)      = *(const bf16x8*)(src);
      *(bf16x8*)(dst + 8)  = *(const bf16x8*)(src + 8);
      *(bf16x8*)(dst + 16) = *(const bf16x8*)(src + 16);
      *(bf16x8*)(dst + 24) = *(const bf16x8*)(src + 24);
      __syncthreads();
    }
    // ---- gates MFMA: wave w = gate w, 2 col-tiles ----
    f32x4 acc0 = {}, acc1 = {};
#pragma unroll
    for (int kk = 0; kk < 16; kk++){
      int kc = kk*32 + lq*8;
      bf16x8 af = *(const bf16x8*)(h_lds + lm*520 + kc);
      bf16x8 b0 = *(const bf16x8*)(ws_lds + (w*32 + lm)*520 + kc);
      bf16x8 b1 = *(const bf16x8*)(ws_lds + (w*32 + 16 + lm)*520 + kc);
      acc0 = __builtin_amdgcn_mfma_f32_16x16x32_bf16(af, b0, acc0, 0, 0, 0);
      acc1 = __builtin_amdgcn_mfma_f32_16x16x32_bf16(af, b1, acc1, 0, 0, 0);
    }
    *(f32x4*)(pre_lds + w*640 + lm*20 + lq*4)        = acc0;
    *(f32x4*)(pre_lds + w*640 + (16 + lm)*20 + lq*4) = acc1;
    __syncthreads();
    // ---- cell update ----
    {
      bool valid = s < Lb;
      int u = dir ? (Lb - 1 - s) : s;
      u = u < 0 ? 0 : u;
      const bf16* xrow = Xpd + (size_t)(u*16 + bb)*16384 + c0g;
      {
        float p0 = pre_lds[0*640 + cc*20 + bb] + (float)xrow[0*4096 + cc];
        float p1 = pre_lds[1*640 + cc*20 + bb] + (float)xrow[1*4096 + cc];
        float p2 = pre_lds[2*640 + cc*20 + bb] + (float)xrow[2*4096 + cc];
        float p3 = pre_lds[3*640 + cc*20 + bb] + (float)xrow[3*4096 + cc];
        float cn = fminf(fmaxf(sigm_(p0)*tanh_(p2) + sigm_(p1)*cs0, -3.f), 3.f);
        if (valid) cs0 = cn;
        abuf[(size_t)(dir*16 + bb)*4096 + c0g + cc] = (bf16)(sigm_(p3) * tanh_(cn));
      }
      {
        int c2 = cc + 16;
        float p0 = pre_lds[0*640 + c2*20 + bb] + (float)xrow[0*4096 + c2];
        float p1 = pre_lds[1*640 + c2*20 + bb] + (float)xrow[1*4096 + c2];
        float p2 = pre_lds[2*640 + c2*20 + bb] + (float)xrow[2*4096 + c2];
        float p3 = pre_lds[3*640 + c2*20 + bb] + (float)xrow[3*4096 + c2];
        float cn = fminf(fmaxf(sigm_(p0)*tanh_(p2) + sigm_(p1)*cs1, -3.f), 3.f);
        if (valid) cs1 = cn;
        abuf[(size_t)(dir*16 + bb)*4096 + c0g + c2] = (bf16)(sigm_(p3) * tanh_(cn));
      }
    }
    // ---- abuf ready: proj wgs announce ep1 then wait for all gates;
    //      non-proj wgs jump straight to ep2 and wait for hfin ----
    set_flag(flags, wg, isproj ? ep1 : ep2);
    if (isproj){
      poll_flags(flags, ep1);
      f32x4 pacc = {};
#pragma unroll
      for (int kk = 0; kk < 32; kk++){
        bf16x8 af = *(const bf16x8*)(ad + (size_t)lm*4096 + w*1024 + kk*32 + lq*8);
        pacc = __builtin_amdgcn_mfma_f32_16x16x32_bf16(af, wp[kk], pacc, 0, 0, 0);
      }
      *(f32x4*)(red_lds + w*320 + lm*20 + lq*4) = pacc;
      __syncthreads();
      {
        int hh = tid >> 4, b = tid & 15;
        float hn_raw = red_lds[0*320 + hh*20 + b] + red_lds[1*320 + hh*20 + b]
                     + red_lds[2*320 + hh*20 + b] + red_lds[3*320 + hh*20 + b];
        bool valid = s < Lpb;
        int idx = (dir*16 + b)*512 + h0 + hh;
        float hold = (float)hfin[idx];
        float hn = valid ? fminf(fmaxf(hn_raw, -3.f), 3.f) : hold;
        hfin[idx] = (bf16)hn;
        if (valid){
          int u = dir ? (Lpb - 1 - s) : s;
          size_t o = ((size_t)(l*16 + b)*128 + u)*1024 + (size_t)dir*512 + h0 + hh;
          float val = hn;
          if (l) val += out[((size_t)b*128 + u)*1024 + (size_t)dir*512 + h0 + hh];
          out[o] = val;
        }
      }
      set_flag(flags, wg, ep2);
    }
    poll_flags(flags, ep2);   // h(s+1) visible to all
  }
}

extern "C" void kernel_launch(void* const* d_in, const int* in_sizes, int n_in,
                              void* d_out, int out_size, void* d_ws, size_t ws_size,
                              hipStream_t stream) {
  const float* x   = (const float*)d_in[0];
  const int*   sl  = (const int*)d_in[1];
  const float* Wi  = (const float*)d_in[2];
  const float* Ws  = (const float*)d_in[3];
  const float* bia = (const float*)d_in[4];
  const float* Wp  = (const float*)d_in[5];
  float* out = (float*)d_out;
  char* ws = (char*)d_ws;

  bf16* WiB = (bf16*)(ws + OFF_WI);
  bf16* WsB = (bf16*)(ws + OFF_WS);
  bf16* WpB = (bf16*)(ws + OFF_WP);
  bf16* A0  = (bf16*)(ws + OFF_A0);
  bf16* A1F = (bf16*)(ws + OFF_A1F);
  bf16* A1B = (bf16*)(ws + OFF_A1B);
  bf16* XpB = (bf16*)(ws + OFF_XP);
  bf16* hfin = (bf16*)(ws + OFF_H);
  bf16* abuf = (bf16*)(ws + OFF_AB);
  int* flags = (int*)(ws + OFF_BAR);

  hipFuncSetAttribute((const void*)k_persist,
                      hipFuncAttributeMaxDynamicSharedMemorySize, 160000);

  // weight casts
  k_cast<<<2048, 256, 0, stream>>>(Wi, WiB, 8388608);
  k_cast<<<2048, 256, 0, stream>>>(Ws, WsB, 8388608);
  k_cast<<<2048, 256, 0, stream>>>(Wp, WpB, 2097152);

  hipMemsetAsync(d_out, 0, (size_t)out_size*4, stream);
  hipMemsetAsync(flags, 0, 4096, stream);

  // ----- layer 0 -----
  k_castx<<<1024, 256, 0, stream>>>(x, A0);
  k_gemm_in<<<dim3(64,32), 256, 0, stream>>>(A0, WiB,           bia,          XpB);
  k_gemm_in<<<dim3(64,32), 256, 0, stream>>>(A0, WiB + WI_SLAB, bia + 16384,  XpB + XP_SLAB);
  k_persist<<<256, 256, 160000, stream>>>(WsB, WpB, XpB, abuf, hfin, sl, out, flags, 0);

  // ----- layer 1 -----
  k_castout<<<2048, 256, 0, stream>>>(out, A1F, A1B);
  k_gemm_in<<<dim3(64,32), 256, 0, stream>>>(A1F, WiB + 2*WI_SLAB, bia + 2*16384, XpB);
  k_gemm_in<<<dim3(64,32), 256, 0, stream>>>(A1B, WiB + 3*WI_SLAB, bia + 3*16384, XpB + XP_SLAB);
  k_persist<<<256, 256, 160000, stream>>>(WsB + 2*WI_SLAB, WpB + 2*WP_SLAB, XpB,
                                          abuf, hfin, sl, out, flags, 1);
}

// Round 4
// 5242.170 us; speedup vs baseline: 6.6957x; 1.7203x over previous
//
#include <hip/hip_runtime.h>
#include <hip/hip_bf16.h>

typedef __bf16 bf16;
typedef unsigned long long ull;
typedef __bf16 bf16x8 __attribute__((ext_vector_type(8)));
typedef __bf16 bf16x4 __attribute__((ext_vector_type(4)));
typedef float f32x4 __attribute__((ext_vector_type(4)));

#define WI_SLAB (16384UL*512UL)
#define WP_SLAB (512UL*4096UL)
#define XP_SLAB (128UL*16UL*16384UL)

// ws byte-offset plan
#define OFF_WI 0UL                       // Wi bf16: 67108864
#define OFF_WS 67108864UL                // Ws bf16: 67108864
#define OFF_WP 134217728UL               // Wp bf16: 16777216
#define OFF_A0 150994944UL               // 2097152
#define OFF_A1F 153092096UL
#define OFF_A1B 155189248UL
#define OFF_XP 157286400UL               // 134217728
#define OFF_H  291504128UL               // hfin: 2*16*512*2 = 32768
#define OFF_BAR 291536896UL              // flags[256*32] ints = 32KB (128B stride)
#define OFF_AB 292061184UL               // abuf: 2*16*4096*2 = 262144

__device__ __forceinline__ float sigm_(float x){ return 1.f/(1.f + __expf(-x)); }
__device__ __forceinline__ float tanh_(float x){ return 1.f - 2.f/(__expf(2.f*x) + 1.f); }

// ---------- generic f32 -> bf16 cast ----------
__global__ __launch_bounds__(256) void k_cast(const float* __restrict__ src,
                                              bf16* __restrict__ dst, int n4){
  int i = blockIdx.x*blockDim.x + threadIdx.x;
  int stride = gridDim.x*blockDim.x;
  const float4* s4 = (const float4*)src;
  bf16x4* d4 = (bf16x4*)dst;
  for (; i < n4; i += stride){
    float4 v = s4[i];
    bf16x4 o = {(bf16)v.x, (bf16)v.y, (bf16)v.z, (bf16)v.w};
    d4[i] = o;
  }
}

// ---------- x (B,T,512) f32 -> A0 (t,b,512) bf16 ----------
__global__ __launch_bounds__(256) void k_castx(const float* __restrict__ x,
                                               bf16* __restrict__ dst){
  int g = blockIdx.x*256 + threadIdx.x;
  int d = (g & 127) * 4;
  int r = g >> 7;
  int b = r >> 7, t = r & 127;
  float4 v = ((const float4*)x)[g];
  bf16x4 o = {(bf16)v.x, (bf16)v.y, (bf16)v.z, (bf16)v.w};
  *(bf16x4*)(dst + (size_t)(t*16 + b)*512 + d) = o;
}

// ---------- layer-0 output (B,T,1024) f32 -> A1f/A1b (t,b,512) bf16 ----------
__global__ __launch_bounds__(256) void k_castout(const float* __restrict__ out0,
                                                 bf16* __restrict__ a1f,
                                                 bf16* __restrict__ a1b){
  int g = blockIdx.x*256 + threadIdx.x;
  int hh = (g & 255) * 4;
  int r = g >> 8;
  int b = r >> 7, t = r & 127;
  float4 v = ((const float4*)out0)[g];
  bf16x4 o = {(bf16)v.x, (bf16)v.y, (bf16)v.z, (bf16)v.w};
  if (hh < 512) *(bf16x4*)(a1f + (size_t)(t*16 + b)*512 + hh) = o;
  else          *(bf16x4*)(a1b + (size_t)(t*16 + b)*512 + hh - 512) = o;
}

// ---------- input GEMM: Xp[m][n] = sum_k A[m][k]*W[n][k] + bias[n] ----------
// grid (32 m-blocks, 64 n-blocks): consecutive blocks share the W n-tile.
__global__ __launch_bounds__(256) void k_gemm_in(const bf16* __restrict__ A,
                                                 const bf16* __restrict__ W,
                                                 const float* __restrict__ bias,
                                                 bf16* __restrict__ Xp){
  int lane = threadIdx.x & 63, w = threadIdx.x >> 6;
  int n0 = blockIdx.y*256 + w*64;
  int m0 = blockIdx.x*64;
  int lm = lane & 15, lq = lane >> 4;
  f32x4 acc[4][4] = {};
  for (int kk = 0; kk < 512; kk += 32){
    int kc = kk + lq*8;
    bf16x8 af[4];
#pragma unroll
    for (int mt = 0; mt < 4; mt++)
      af[mt] = *(const bf16x8*)(A + (size_t)(m0 + mt*16 + lm)*512 + kc);
#pragma unroll
    for (int nt = 0; nt < 4; nt++){
      bf16x8 bfr = *(const bf16x8*)(W + (size_t)(n0 + nt*16 + lm)*512 + kc);
#pragma unroll
      for (int mt = 0; mt < 4; mt++)
        acc[mt][nt] = __builtin_amdgcn_mfma_f32_16x16x32_bf16(af[mt], bfr, acc[mt][nt], 0, 0, 0);
    }
  }
#pragma unroll
  for (int mt = 0; mt < 4; mt++)
#pragma unroll
    for (int nt = 0; nt < 4; nt++)
#pragma unroll
      for (int r = 0; r < 4; r++){
        int row = m0 + mt*16 + lq*4 + r;
        int col = n0 + nt*16 + lm;
        Xp[(size_t)row*16384 + col] = (bf16)(acc[mt][nt][r] + bias[col]);
      }
}

// ---------- flag primitives: relaxed agent atomics only (sc1 -> L3), ----------
// ---------- ZERO cache-maintenance instructions (no wbl2 / no inv).  ----------
// Flags padded to 32 ints (128B) to spread L3 banks.
__device__ __forceinline__ void set_flag(int* flags, int wg, int ep){
  __syncthreads();  // drains vmcnt: all prior sc1 data stores are acked by L3
  __atomic_signal_fence(__ATOMIC_SEQ_CST);
  if (threadIdx.x == 0)
    __hip_atomic_store(flags + wg*32, ep, __ATOMIC_RELAXED, __HIP_MEMORY_SCOPE_AGENT);
}
__device__ __forceinline__ void poll_all(int* flags, int ep){
  if (threadIdx.x < 64){
    int i0 = threadIdx.x * 4;
    for (;;){
      int f0 = __hip_atomic_load(flags + (i0+0)*32, __ATOMIC_RELAXED, __HIP_MEMORY_SCOPE_AGENT);
      int f1 = __hip_atomic_load(flags + (i0+1)*32, __ATOMIC_RELAXED, __HIP_MEMORY_SCOPE_AGENT);
      int f2 = __hip_atomic_load(flags + (i0+2)*32, __ATOMIC_RELAXED, __HIP_MEMORY_SCOPE_AGENT);
      int f3 = __hip_atomic_load(flags + (i0+3)*32, __ATOMIC_RELAXED, __HIP_MEMORY_SCOPE_AGENT);
      if (__all((f0 >= ep) && (f1 >= ep) && (f2 >= ep) && (f3 >= ep))) break;
      __builtin_amdgcn_s_sleep(1);
    }
  }
  __atomic_signal_fence(__ATOMIC_SEQ_CST);
  __syncthreads();
}
// poll only the 64 proj wgs' flags (indices 0..31 and 128..159)
__device__ __forceinline__ void poll_proj(int* flags, int ep){
  if (threadIdx.x < 64){
    int fi = (int)threadIdx.x + (((int)threadIdx.x >> 5) * 96);
    for (;;){
      int f = __hip_atomic_load(flags + fi*32, __ATOMIC_RELAXED, __HIP_MEMORY_SCOPE_AGENT);
      if (__all(f >= ep)) break;
      __builtin_amdgcn_s_sleep(1);
    }
  }
  __atomic_signal_fence(__ATOMIC_SEQ_CST);
  __syncthreads();
}

// ---------- persistent recurrence kernel (one layer, both dirs) ----------
// 256 wgs x 256 thr, 1 wg/CU. dir = wg>>7, sub = wg&127.
// All wgs: gates for 32 columns, Ws slice (130KB) in LDS.
// sub<32 wgs additionally: projection h-tile sub*16..+16 (Wp from L2).
// Cross-XCD data (abuf, hfin, flags) moves via relaxed agent atomics (sc1/L3);
// everything else (Xp, Ws, Wp, out) uses normal cached paths, never invalidated.
__global__ __launch_bounds__(256, 1) void k_persist(
    const bf16* __restrict__ Wsl, const bf16* __restrict__ Wpl,
    const bf16* __restrict__ Xp, bf16* __restrict__ abuf,
    bf16* __restrict__ hfin, const int* __restrict__ len,
    float* __restrict__ out, int* __restrict__ flags, int l)
{
  extern __shared__ char smem[];
  bf16* ws_lds  = (bf16*)smem;                     // 128 rows x 520 = 133120 B
  bf16* h_lds   = (bf16*)(smem + 133120);          // 16 x 520 = 16640 B
  float* pre_lds = (float*)(smem + 149760);        // [4g][32c][20b] f32 = 10240 B
  float* red_lds = pre_lds;                        // proj reduction reuse [4w][16h][20b]

  const int tid = threadIdx.x;
  const int lane = tid & 63, w = tid >> 6;
  const int lm = lane & 15, lq = lane >> 4;
  const int wg = blockIdx.x;
  const int dir = wg >> 7;
  const int sub = wg & 127;
  const int c0g = sub * 32;
  const bool isproj = (sub < 32);

  const bf16* Wsd = Wsl + (size_t)dir * WI_SLAB;
  const bf16* Wpd = Wpl + (size_t)dir * WP_SLAB;
  const bf16* Xpd = Xp + (size_t)dir * XP_SLAB;
  unsigned int* abw = (unsigned int*)abuf;
  const ull* adw = (const ull*)abuf + (size_t)dir * 16 * 1024;   // 4096 bf16 = 1024 ull/row
  unsigned int* hfw = (unsigned int*)hfin;

  // ---- Ws slice -> LDS (once per layer) ----
  {
    int rr = tid >> 1, half = tid & 1;
    int g = rr >> 5, c = rr & 31;
    const bf16* src = Wsd + ((size_t)(g*4096 + c0g + c))*512 + half*256;
    bf16* dst = ws_lds + rr*520 + half*256;
#pragma unroll
    for (int i = 0; i < 32; i++)
      ((bf16x8*)dst)[i] = ((const bf16x8*)src)[i];
  }
  // ---- zero h_lds ----
  for (int i = tid; i < 4160; i += 256) ((unsigned int*)h_lds)[i] = 0u;

  const int h0 = (sub & 31) * 16;
  float cs0 = 0.f, cs1 = 0.f;                 // cell state, thread-owned
  float h_prev = 0.f;                         // proj: carried h for invalid steps
  const int bb = tid >> 4;                    // gate/cell batch row
  const int cc = tid & 15;
  const int Lb = len[bb];
  __syncthreads();

  for (int s = 0; s < 128; s++){
    const int ep1 = l*256 + s*2 + 1;
    const int ep2 = ep1 + 1;
    // ---- stage h(s) into LDS via L3-coherent loads ----
    if (s > 0){
      const ull* src = (const ull*)hfin + (size_t)(dir*16 + bb)*128 + cc*8;
      ull* dst = (ull*)(h_lds + bb*520 + cc*32);
#pragma unroll
      for (int i = 0; i < 8; i++)
        dst[i] = __hip_atomic_load(src + i, __ATOMIC_RELAXED, __HIP_MEMORY_SCOPE_AGENT);
      __syncthreads();
    }
    // ---- gates MFMA: wave w = gate w, 2 col-tiles ----
    f32x4 acc0 = {}, acc1 = {};
#pragma unroll
    for (int kk = 0; kk < 16; kk++){
      int kc = kk*32 + lq*8;
      bf16x8 af = *(const bf16x8*)(h_lds + lm*520 + kc);
      bf16x8 b0 = *(const bf16x8*)(ws_lds + (w*32 + lm)*520 + kc);
      bf16x8 b1 = *(const bf16x8*)(ws_lds + (w*32 + 16 + lm)*520 + kc);
      acc0 = __builtin_amdgcn_mfma_f32_16x16x32_bf16(af, b0, acc0, 0, 0, 0);
      acc1 = __builtin_amdgcn_mfma_f32_16x16x32_bf16(af, b1, acc1, 0, 0, 0);
    }
    *(f32x4*)(pre_lds + w*640 + lm*20 + lq*4)        = acc0;
    *(f32x4*)(pre_lds + w*640 + (16 + lm)*20 + lq*4) = acc1;
    __syncthreads();
    // ---- cell update: thread (bb, cc) owns columns 2cc, 2cc+1 ----
    {
      bool valid = s < Lb;
      int u = dir ? (Lb - 1 - s) : s;
      u = u < 0 ? 0 : u;
      const bf16* xrow = Xpd + (size_t)(u*16 + bb)*16384 + c0g + 2*cc;
      float p0[4], p1[4];
#pragma unroll
      for (int g = 0; g < 4; g++){
        p0[g] = pre_lds[g*640 + (2*cc)*20 + bb]   + (float)xrow[g*4096];
        p1[g] = pre_lds[g*640 + (2*cc+1)*20 + bb] + (float)xrow[g*4096 + 1];
      }
      float cn0 = fminf(fmaxf(sigm_(p0[0])*tanh_(p0[2]) + sigm_(p0[1])*cs0, -3.f), 3.f);
      float cn1 = fminf(fmaxf(sigm_(p1[0])*tanh_(p1[2]) + sigm_(p1[1])*cs1, -3.f), 3.f);
      if (valid){ cs0 = cn0; cs1 = cn1; }
      float a0 = sigm_(p0[3]) * tanh_(cn0);
      float a1 = sigm_(p1[3]) * tanh_(cn1);
      unsigned int pk = ((unsigned int)__builtin_bit_cast(unsigned short, (bf16)a1) << 16)
                      |  (unsigned int)__builtin_bit_cast(unsigned short, (bf16)a0);
      __hip_atomic_store(abw + (size_t)(dir*16 + bb)*2048 + (c0g >> 1) + cc, pk,
                         __ATOMIC_RELAXED, __HIP_MEMORY_SCOPE_AGENT);
    }
    // ---- announce: proj -> ep1 then wait all; gates -> ep2 and wait for proj ----
    set_flag(flags, wg, isproj ? ep1 : ep2);
    if (isproj){
      poll_all(flags, ep1);
      f32x4 pacc = {};
#pragma unroll
      for (int kk = 0; kk < 32; kk++){
        size_t ai = (size_t)lm*1024 + w*256 + kk*8 + lq*2;
        ull qlo = __hip_atomic_load(adw + ai,     __ATOMIC_RELAXED, __HIP_MEMORY_SCOPE_AGENT);
        ull qhi = __hip_atomic_load(adw + ai + 1, __ATOMIC_RELAXED, __HIP_MEMORY_SCOPE_AGENT);
        union { ull q[2]; bf16x8 v; } ua; ua.q[0] = qlo; ua.q[1] = qhi;
        bf16x8 wrow = *(const bf16x8*)(Wpd + (size_t)(h0 + lm)*4096 + w*1024 + kk*32 + lq*8);
        pacc = __builtin_amdgcn_mfma_f32_16x16x32_bf16(ua.v, wrow, pacc, 0, 0, 0);
      }
      *(f32x4*)(red_lds + w*320 + lm*20 + lq*4) = pacc;   // [hcol=lm][batch=lq*4+r]
      __syncthreads();
      {
        int b = tid >> 4, hh = tid & 15;
        float hn_raw = red_lds[0*320 + hh*20 + b] + red_lds[1*320 + hh*20 + b]
                     + red_lds[2*320 + hh*20 + b] + red_lds[3*320 + hh*20 + b];
        int Lpb = len[b];
        bool valid = s < Lpb;
        float hn = valid ? fminf(fmaxf(hn_raw, -3.f), 3.f) : h_prev;
        h_prev = hn;
        unsigned int hb = (unsigned int)__builtin_bit_cast(unsigned short, (bf16)hn);
        unsigned int ob = (unsigned int)__shfl_xor((int)hb, 1, 64);
        if (!(hh & 1)){
          unsigned int pk = (ob << 16) | hb;
          __hip_atomic_store(hfw + (((dir*16 + b)*512 + h0 + hh) >> 1), pk,
                             __ATOMIC_RELAXED, __HIP_MEMORY_SCOPE_AGENT);
        }
        if (valid){
          int u = dir ? (Lpb - 1 - s) : s;
          size_t o = ((size_t)(l*16 + b)*128 + u)*1024 + (size_t)dir*512 + h0 + hh;
          float val = hn;
          if (l) val += out[((size_t)b*128 + u)*1024 + (size_t)dir*512 + h0 + hh];
          out[o] = val;
        }
      }
      set_flag(flags, wg, ep2);
    }
    poll_proj(flags, ep2);   // h(s+1) visible to all
  }
}

extern "C" void kernel_launch(void* const* d_in, const int* in_sizes, int n_in,
                              void* d_out, int out_size, void* d_ws, size_t ws_size,
                              hipStream_t stream) {
  const float* x   = (const float*)d_in[0];
  const int*   sl  = (const int*)d_in[1];
  const float* Wi  = (const float*)d_in[2];
  const float* Ws  = (const float*)d_in[3];
  const float* bia = (const float*)d_in[4];
  const float* Wp  = (const float*)d_in[5];
  float* out = (float*)d_out;
  char* ws = (char*)d_ws;

  bf16* WiB = (bf16*)(ws + OFF_WI);
  bf16* WsB = (bf16*)(ws + OFF_WS);
  bf16* WpB = (bf16*)(ws + OFF_WP);
  bf16* A0  = (bf16*)(ws + OFF_A0);
  bf16* A1F = (bf16*)(ws + OFF_A1F);
  bf16* A1B = (bf16*)(ws + OFF_A1B);
  bf16* XpB = (bf16*)(ws + OFF_XP);
  bf16* hfin = (bf16*)(ws + OFF_H);
  bf16* abuf = (bf16*)(ws + OFF_AB);
  int* flags = (int*)(ws + OFF_BAR);

  hipFuncSetAttribute((const void*)k_persist,
                      hipFuncAttributeMaxDynamicSharedMemorySize, 160000);

  // weight casts
  k_cast<<<2048, 256, 0, stream>>>(Wi, WiB, 8388608);
  k_cast<<<2048, 256, 0, stream>>>(Ws, WsB, 8388608);
  k_cast<<<2048, 256, 0, stream>>>(Wp, WpB, 2097152);

  hipMemsetAsync(d_out, 0, (size_t)out_size*4, stream);
  hipMemsetAsync(flags, 0, 32768, stream);

  // ----- layer 0 -----
  k_castx<<<1024, 256, 0, stream>>>(x, A0);
  k_gemm_in<<<dim3(32,64), 256, 0, stream>>>(A0, WiB,           bia,          XpB);
  k_gemm_in<<<dim3(32,64), 256, 0, stream>>>(A0, WiB + WI_SLAB, bia + 16384,  XpB + XP_SLAB);
  k_persist<<<256, 256, 160000, stream>>>(WsB, WpB, XpB, abuf, hfin, sl, out, flags, 0);

  // ----- layer 1 -----
  k_castout<<<2048, 256, 0, stream>>>(out, A1F, A1B);
  k_gemm_in<<<dim3(32,64), 256, 0, stream>>>(A1F, WiB + 2*WI_SLAB, bia + 2*16384, XpB);
  k_gemm_in<<<dim3(32,64), 256, 0, stream>>>(A1B, WiB + 3*WI_SLAB, bia + 3*16384, XpB + XP_SLAB);
  k_persist<<<256, 256, 160000, stream>>>(WsB + 2*WI_SLAB, WpB + 2*WP_SLAB, XpB,
                                          abuf, hfin, sl, out, flags, 1);
}

// Round 5
// 4867.330 us; speedup vs baseline: 7.2113x; 1.0770x over previous
//
#include <hip/hip_runtime.h>
#include <hip/hip_bf16.h>

typedef __bf16 bf16;
typedef unsigned long long ull;
typedef __bf16 bf16x8 __attribute__((ext_vector_type(8)));
typedef __bf16 bf16x4 __attribute__((ext_vector_type(4)));
typedef float f32x4 __attribute__((ext_vector_type(4)));

#define WI_SLAB (16384UL*512UL)
#define WP_SLAB (512UL*4096UL)
#define XP_SLAB (128UL*16UL*16384UL)

// ws byte-offset plan
#define OFF_WI 0UL                       // Wi bf16: 67108864
#define OFF_WS 67108864UL                // Ws bf16: 67108864
#define OFF_WP 134217728UL               // Wp bf16: 16777216
#define OFF_A0 150994944UL               // 2097152
#define OFF_A1F 153092096UL
#define OFF_A1B 155189248UL
#define OFF_XP 157286400UL               // 134217728
#define OFF_H  291504128UL               // hfin: 2*16*512*2 = 32768
#define OFF_BAR 291536896UL              // flags[256*32] ints = 32KB (128B stride)
#define OFF_AB 292061184UL               // abuf: 2*16*4096*2 = 262144

__device__ __forceinline__ float sigm_(float x){ return 1.f/(1.f + __expf(-x)); }
__device__ __forceinline__ float tanh_(float x){ return 1.f - 2.f/(__expf(2.f*x) + 1.f); }
__device__ __forceinline__ float bfl_(unsigned int u){   // low bf16 of packed word
  return __builtin_bit_cast(float, u << 16);
}
__device__ __forceinline__ float bfh_(unsigned int u){   // high bf16
  return __builtin_bit_cast(float, u & 0xffff0000u);
}

// ---------- generic f32 -> bf16 cast ----------
__global__ __launch_bounds__(256) void k_cast(const float* __restrict__ src,
                                              bf16* __restrict__ dst, int n4){
  int i = blockIdx.x*blockDim.x + threadIdx.x;
  int stride = gridDim.x*blockDim.x;
  const float4* s4 = (const float4*)src;
  bf16x4* d4 = (bf16x4*)dst;
  for (; i < n4; i += stride){
    float4 v = s4[i];
    bf16x4 o = {(bf16)v.x, (bf16)v.y, (bf16)v.z, (bf16)v.w};
    d4[i] = o;
  }
}

// ---------- x (B,T,512) f32 -> A0 (t,b,512) bf16 ----------
__global__ __launch_bounds__(256) void k_castx(const float* __restrict__ x,
                                               bf16* __restrict__ dst){
  int g = blockIdx.x*256 + threadIdx.x;
  int d = (g & 127) * 4;
  int r = g >> 7;
  int b = r >> 7, t = r & 127;
  float4 v = ((const float4*)x)[g];
  bf16x4 o = {(bf16)v.x, (bf16)v.y, (bf16)v.z, (bf16)v.w};
  *(bf16x4*)(dst + (size_t)(t*16 + b)*512 + d) = o;
}

// ---------- layer-0 output (B,T,1024) f32 -> A1f/A1b (t,b,512) bf16 ----------
__global__ __launch_bounds__(256) void k_castout(const float* __restrict__ out0,
                                                 bf16* __restrict__ a1f,
                                                 bf16* __restrict__ a1b){
  int g = blockIdx.x*256 + threadIdx.x;
  int hh = (g & 255) * 4;
  int r = g >> 8;
  int b = r >> 7, t = r & 127;
  float4 v = ((const float4*)out0)[g];
  bf16x4 o = {(bf16)v.x, (bf16)v.y, (bf16)v.z, (bf16)v.w};
  if (hh < 512) *(bf16x4*)(a1f + (size_t)(t*16 + b)*512 + hh) = o;
  else          *(bf16x4*)(a1b + (size_t)(t*16 + b)*512 + hh - 512) = o;
}

// ---------- input GEMM: Xp[m][n] = sum_k A[m][k]*W[n][k] + bias[n] ----------
__global__ __launch_bounds__(256) void k_gemm_in(const bf16* __restrict__ A,
                                                 const bf16* __restrict__ W,
                                                 const float* __restrict__ bias,
                                                 bf16* __restrict__ Xp){
  int lane = threadIdx.x & 63, w = threadIdx.x >> 6;
  int n0 = blockIdx.y*256 + w*64;
  int m0 = blockIdx.x*64;
  int lm = lane & 15, lq = lane >> 4;
  f32x4 acc[4][4] = {};
  for (int kk = 0; kk < 512; kk += 32){
    int kc = kk + lq*8;
    bf16x8 af[4];
#pragma unroll
    for (int mt = 0; mt < 4; mt++)
      af[mt] = *(const bf16x8*)(A + (size_t)(m0 + mt*16 + lm)*512 + kc);
#pragma unroll
    for (int nt = 0; nt < 4; nt++){
      bf16x8 bfr = *(const bf16x8*)(W + (size_t)(n0 + nt*16 + lm)*512 + kc);
#pragma unroll
      for (int mt = 0; mt < 4; mt++)
        acc[mt][nt] = __builtin_amdgcn_mfma_f32_16x16x32_bf16(af[mt], bfr, acc[mt][nt], 0, 0, 0);
    }
  }
#pragma unroll
  for (int mt = 0; mt < 4; mt++)
#pragma unroll
    for (int nt = 0; nt < 4; nt++)
#pragma unroll
      for (int r = 0; r < 4; r++){
        int row = m0 + mt*16 + lq*4 + r;
        int col = n0 + nt*16 + lm;
        Xp[(size_t)row*16384 + col] = (bf16)(acc[mt][nt][r] + bias[col]);
      }
}

// ---------- flag primitives: relaxed agent atomics (sc1 -> L3), no wbl2/inv ----
__device__ __forceinline__ void set_flag(int* flags, int wg, int ep){
  __syncthreads();  // drains vmcnt: all prior sc1 data stores acked by L3
  __atomic_signal_fence(__ATOMIC_SEQ_CST);
  if (threadIdx.x == 0)
    __hip_atomic_store(flags + wg*32, ep, __ATOMIC_RELAXED, __HIP_MEMORY_SCOPE_AGENT);
}
// wait for the 128 gate wgs of one dir (wgs dir*128 .. dir*128+127)
__device__ __forceinline__ void poll_gates_dir(int* flags, int dir, int ep){
  if (threadIdx.x < 32){
    int base = dir*128 + (int)threadIdx.x*4;
    for (;;){
      int f0 = __hip_atomic_load(flags + (base+0)*32, __ATOMIC_RELAXED, __HIP_MEMORY_SCOPE_AGENT);
      int f1 = __hip_atomic_load(flags + (base+1)*32, __ATOMIC_RELAXED, __HIP_MEMORY_SCOPE_AGENT);
      int f2 = __hip_atomic_load(flags + (base+2)*32, __ATOMIC_RELAXED, __HIP_MEMORY_SCOPE_AGENT);
      int f3 = __hip_atomic_load(flags + (base+3)*32, __ATOMIC_RELAXED, __HIP_MEMORY_SCOPE_AGENT);
      if (__all((f0 >= ep) && (f1 >= ep) && (f2 >= ep) && (f3 >= ep))) break;
      __builtin_amdgcn_s_sleep(1);
    }
  }
  __atomic_signal_fence(__ATOMIC_SEQ_CST);
  __syncthreads();
}
// wait for the 32 proj wgs of one dir (wgs dir*128 .. dir*128+31)
__device__ __forceinline__ void poll_proj_dir(int* flags, int dir, int ep){
  if (threadIdx.x < 32){
    int fi = dir*128 + (int)threadIdx.x;
    for (;;){
      int f = __hip_atomic_load(flags + fi*32, __ATOMIC_RELAXED, __HIP_MEMORY_SCOPE_AGENT);
      if (__all(f >= ep)) break;
      __builtin_amdgcn_s_sleep(1);
    }
  }
  __atomic_signal_fence(__ATOMIC_SEQ_CST);
  __syncthreads();
}

// ---------- persistent recurrence kernel (one layer, both dirs) ----------
// 256 wgs x 256 thr, 1 wg/CU. dir = wg>>7, sub = wg&127.
// All wgs: gates for 32 columns, Ws slice (130KB) in LDS.
// sub<32 wgs additionally: projection h-tile sub*16..+16 (Wp from L2).
// Directions fully decoupled (per-dir flag sets). Xp rows prefetched one step
// ahead into registers so HBM latency lands inside the barrier wait.
__global__ __launch_bounds__(256, 1) void k_persist(
    const bf16* __restrict__ Wsl, const bf16* __restrict__ Wpl,
    const bf16* __restrict__ Xp, bf16* __restrict__ abuf,
    bf16* __restrict__ hfin, const int* __restrict__ len,
    float* __restrict__ out, int* __restrict__ flags, int l)
{
  extern __shared__ char smem[];
  bf16* ws_lds  = (bf16*)smem;                     // 128 rows x 520 = 133120 B
  bf16* h_lds   = (bf16*)(smem + 133120);          // 16 x 520 = 16640 B
  float* pre_lds = (float*)(smem + 149760);        // [4g][32c][20b] f32 = 10240 B
  float* red_lds = pre_lds;                        // proj reduction reuse [4w][16h][20b]

  const int tid = threadIdx.x;
  const int lane = tid & 63, w = tid >> 6;
  const int lm = lane & 15, lq = lane >> 4;
  const int wg = blockIdx.x;
  const int dir = wg >> 7;
  const int sub = wg & 127;
  const int c0g = sub * 32;
  const bool isproj = (sub < 32);

  const bf16* Wsd = Wsl + (size_t)dir * WI_SLAB;
  const bf16* Wpd = Wpl + (size_t)dir * WP_SLAB;
  const bf16* Xpd = Xp + (size_t)dir * XP_SLAB;
  unsigned int* abw = (unsigned int*)abuf;
  const ull* adw = (const ull*)abuf + (size_t)dir * 16 * 1024;
  unsigned int* hfw = (unsigned int*)hfin;

  // ---- Ws slice -> LDS (once per layer) ----
  {
    int rr = tid >> 1, half = tid & 1;
    int g = rr >> 5, c = rr & 31;
    const bf16* src = Wsd + ((size_t)(g*4096 + c0g + c))*512 + half*256;
    bf16* dst = ws_lds + rr*520 + half*256;
#pragma unroll
    for (int i = 0; i < 32; i++)
      ((bf16x8*)dst)[i] = ((const bf16x8*)src)[i];
  }
  for (int i = tid; i < 4160; i += 256) ((unsigned int*)h_lds)[i] = 0u;

  const int h0 = (sub & 31) * 16;
  float cs0 = 0.f, cs1 = 0.f;                 // cell state, thread-owned
  float h_prev = 0.f;                         // proj: carried h for invalid steps
  const int bb = tid >> 4;                    // gate/cell batch row
  const int cc = tid & 15;
  const int Lb = len[bb];
  int Lmax = len[0];
#pragma unroll
  for (int b = 1; b < 16; b++){ int v = len[b]; Lmax = v > Lmax ? v : Lmax; }

  // Xp prefetch: thread (bb,cc) needs packed pair (cols c0g+2cc, +1) per gate.
  const unsigned int* xbase = (const unsigned int*)Xpd + (c0g >> 1) + cc;
  unsigned int xp_pre[4];
  {
    int u = dir ? (Lb - 1) : 0;
    u = u < 0 ? 0 : u;
    const unsigned int* xr = xbase + (size_t)(u*16 + bb)*8192;
#pragma unroll
    for (int g = 0; g < 4; g++) xp_pre[g] = xr[g*2048];
  }
  __syncthreads();

  for (int s = 0; s < Lmax; s++){
    const int ep1 = l*256 + s*2 + 1;
    const int ep2 = ep1 + 1;
    // ---- stage h(s) into LDS via L3-coherent loads ----
    if (s > 0){
      const ull* src = (const ull*)hfin + (size_t)(dir*16 + bb)*128 + cc*8;
      ull* dst = (ull*)(h_lds + bb*520 + cc*32);
#pragma unroll
      for (int i = 0; i < 8; i++)
        dst[i] = __hip_atomic_load(src + i, __ATOMIC_RELAXED, __HIP_MEMORY_SCOPE_AGENT);
      __syncthreads();
    }
    // ---- gates MFMA: wave w = gate w, 2 col-tiles ----
    f32x4 acc0 = {}, acc1 = {};
#pragma unroll
    for (int kk = 0; kk < 16; kk++){
      int kc = kk*32 + lq*8;
      bf16x8 af = *(const bf16x8*)(h_lds + lm*520 + kc);
      bf16x8 b0 = *(const bf16x8*)(ws_lds + (w*32 + lm)*520 + kc);
      bf16x8 b1 = *(const bf16x8*)(ws_lds + (w*32 + 16 + lm)*520 + kc);
      acc0 = __builtin_amdgcn_mfma_f32_16x16x32_bf16(af, b0, acc0, 0, 0, 0);
      acc1 = __builtin_amdgcn_mfma_f32_16x16x32_bf16(af, b1, acc1, 0, 0, 0);
    }
    *(f32x4*)(pre_lds + w*640 + lm*20 + lq*4)        = acc0;
    *(f32x4*)(pre_lds + w*640 + (16 + lm)*20 + lq*4) = acc1;
    __syncthreads();
    // ---- cell update: thread (bb, cc) owns columns 2cc, 2cc+1 ----
    {
      bool valid = s < Lb;
      float p0[4], p1[4];
#pragma unroll
      for (int g = 0; g < 4; g++){
        p0[g] = pre_lds[g*640 + (2*cc)*20 + bb]   + bfl_(xp_pre[g]);
        p1[g] = pre_lds[g*640 + (2*cc+1)*20 + bb] + bfh_(xp_pre[g]);
      }
      float cn0 = fminf(fmaxf(sigm_(p0[0])*tanh_(p0[2]) + sigm_(p0[1])*cs0, -3.f), 3.f);
      float cn1 = fminf(fmaxf(sigm_(p1[0])*tanh_(p1[2]) + sigm_(p1[1])*cs1, -3.f), 3.f);
      if (valid){ cs0 = cn0; cs1 = cn1; }
      float a0 = sigm_(p0[3]) * tanh_(cn0);
      float a1 = sigm_(p1[3]) * tanh_(cn1);
      unsigned int pk = ((unsigned int)__builtin_bit_cast(unsigned short, (bf16)a1) << 16)
                      |  (unsigned int)__builtin_bit_cast(unsigned short, (bf16)a0);
      __hip_atomic_store(abw + (size_t)(dir*16 + bb)*2048 + (c0g >> 1) + cc, pk,
                         __ATOMIC_RELAXED, __HIP_MEMORY_SCOPE_AGENT);
    }
    // ---- announce; then prefetch next step's Xp while waiting ----
    set_flag(flags, wg, isproj ? ep1 : ep2);
    {
      int sn = s + 1;
      int u = dir ? (Lb - 1 - sn) : sn;
      u = u < 0 ? 0 : (u > 127 ? 127 : u);
      const unsigned int* xr = xbase + (size_t)(u*16 + bb)*8192;
#pragma unroll
      for (int g = 0; g < 4; g++) xp_pre[g] = xr[g*2048];
    }
    if (isproj){
      poll_gates_dir(flags, dir, ep1);
      f32x4 pacc = {};
#pragma unroll
      for (int kk = 0; kk < 32; kk++){
        size_t ai = (size_t)lm*1024 + w*256 + kk*8 + lq*2;
        ull qlo = __hip_atomic_load(adw + ai,     __ATOMIC_RELAXED, __HIP_MEMORY_SCOPE_AGENT);
        ull qhi = __hip_atomic_load(adw + ai + 1, __ATOMIC_RELAXED, __HIP_MEMORY_SCOPE_AGENT);
        union { ull q[2]; bf16x8 v; } ua; ua.q[0] = qlo; ua.q[1] = qhi;
        bf16x8 wrow = *(const bf16x8*)(Wpd + (size_t)(h0 + lm)*4096 + w*1024 + kk*32 + lq*8);
        pacc = __builtin_amdgcn_mfma_f32_16x16x32_bf16(ua.v, wrow, pacc, 0, 0, 0);
      }
      *(f32x4*)(red_lds + w*320 + lm*20 + lq*4) = pacc;
      __syncthreads();
      {
        int b = tid >> 4, hh = tid & 15;
        float hn_raw = red_lds[0*320 + hh*20 + b] + red_lds[1*320 + hh*20 + b]
                     + red_lds[2*320 + hh*20 + b] + red_lds[3*320 + hh*20 + b];
        int Lpb = len[b];
        bool valid = s < Lpb;
        float hn = valid ? fminf(fmaxf(hn_raw, -3.f), 3.f) : h_prev;
        h_prev = hn;
        unsigned int hb = (unsigned int)__builtin_bit_cast(unsigned short, (bf16)hn);
        unsigned int ob = (unsigned int)__shfl_xor((int)hb, 1, 64);
        if (!(hh & 1)){
          unsigned int pk = (ob << 16) | hb;
          __hip_atomic_store(hfw + (((dir*16 + b)*512 + h0 + hh) >> 1), pk,
                             __ATOMIC_RELAXED, __HIP_MEMORY_SCOPE_AGENT);
        }
        if (valid){
          int u = dir ? (Lpb - 1 - s) : s;
          size_t o = ((size_t)(l*16 + b)*128 + u)*1024 + (size_t)dir*512 + h0 + hh;
          float val = hn;
          if (l) val += out[((size_t)b*128 + u)*1024 + (size_t)dir*512 + h0 + hh];
          out[o] = val;
        }
      }
      set_flag(flags, wg, ep2);
    }
    poll_proj_dir(flags, dir, ep2);   // h(s+1) visible to all in this dir
  }
}

extern "C" void kernel_launch(void* const* d_in, const int* in_sizes, int n_in,
                              void* d_out, int out_size, void* d_ws, size_t ws_size,
                              hipStream_t stream) {
  const float* x   = (const float*)d_in[0];
  const int*   sl  = (const int*)d_in[1];
  const float* Wi  = (const float*)d_in[2];
  const float* Ws  = (const float*)d_in[3];
  const float* bia = (const float*)d_in[4];
  const float* Wp  = (const float*)d_in[5];
  float* out = (float*)d_out;
  char* ws = (char*)d_ws;

  bf16* WiB = (bf16*)(ws + OFF_WI);
  bf16* WsB = (bf16*)(ws + OFF_WS);
  bf16* WpB = (bf16*)(ws + OFF_WP);
  bf16* A0  = (bf16*)(ws + OFF_A0);
  bf16* A1F = (bf16*)(ws + OFF_A1F);
  bf16* A1B = (bf16*)(ws + OFF_A1B);
  bf16* XpB = (bf16*)(ws + OFF_XP);
  bf16* hfin = (bf16*)(ws + OFF_H);
  bf16* abuf = (bf16*)(ws + OFF_AB);
  int* flags = (int*)(ws + OFF_BAR);

  hipFuncSetAttribute((const void*)k_persist,
                      hipFuncAttributeMaxDynamicSharedMemorySize, 160000);

  // weight casts
  k_cast<<<2048, 256, 0, stream>>>(Wi, WiB, 8388608);
  k_cast<<<2048, 256, 0, stream>>>(Ws, WsB, 8388608);
  k_cast<<<2048, 256, 0, stream>>>(Wp, WpB, 2097152);

  hipMemsetAsync(d_out, 0, (size_t)out_size*4, stream);
  hipMemsetAsync(flags, 0, 32768, stream);

  // ----- layer 0 -----
  k_castx<<<1024, 256, 0, stream>>>(x, A0);
  k_gemm_in<<<dim3(32,64), 256, 0, stream>>>(A0, WiB,           bia,          XpB);
  k_gemm_in<<<dim3(32,64), 256, 0, stream>>>(A0, WiB + WI_SLAB, bia + 16384,  XpB + XP_SLAB);
  k_persist<<<256, 256, 160000, stream>>>(WsB, WpB, XpB, abuf, hfin, sl, out, flags, 0);

  // ----- layer 1 -----
  k_castout<<<2048, 256, 0, stream>>>(out, A1F, A1B);
  k_gemm_in<<<dim3(32,64), 256, 0, stream>>>(A1F, WiB + 2*WI_SLAB, bia + 2*16384, XpB);
  k_gemm_in<<<dim3(32,64), 256, 0, stream>>>(A1B, WiB + 3*WI_SLAB, bia + 3*16384, XpB + XP_SLAB);
  k_persist<<<256, 256, 160000, stream>>>(WsB + 2*WI_SLAB, WpB + 2*WP_SLAB, XpB,
                                          abuf, hfin, sl, out, flags, 1);
}